// Round 14
// baseline (221.014 us; speedup 1.0000x reference)
//
#include <hip/hip_runtime.h>
#include <hip/hip_bf16.h>

// Problem constants (B, D, H, W) = (8, 128, 64, 64)
#define B_   8
#define D_   128
#define N_   4096
#define CH   259            // 2D+3 output channels

typedef short bf8 __attribute__((ext_vector_type(8)));   // 8 bf16 (MFMA A/B frag)
typedef float f4  __attribute__((ext_vector_type(4)));   // MFMA C/D frag

typedef unsigned int as1_u32 __attribute__((address_space(1)));
typedef unsigned int as3_u32 __attribute__((address_space(3)));

__device__ __forceinline__ void gll16(const void* g, void* l) {
    // async global->LDS, 16B/lane; LDS dest = wave-uniform base (HW adds lane*16)
    __builtin_amdgcn_global_load_lds((as1_u32*)(unsigned long long)g,
                                     (as3_u32*)(unsigned int)(unsigned long long)l,
                                     16, 0, 0);
}

__device__ __forceinline__ unsigned int cvtpk(float lo, float hi) {
    unsigned int r;
    asm("v_cvt_pk_bf16_f32 %0, %1, %2" : "=v"(r) : "v"(lo), "v"(hi));
    return r;
}

// ---------------------------------------------------------------------------
// Kernel 1: W fp32 -> bf16 (RNE), layout [3][o][d]. Vectorized: 12288 float4.
// ---------------------------------------------------------------------------
__global__ __launch_bounds__(256) void wconv_kernel(
    const float* __restrict__ Wq, const float* __restrict__ Wk,
    const float* __restrict__ Wv, unsigned short* __restrict__ Wb) {
    const int idx = blockIdx.x * 256 + threadIdx.x;     // 48 blocks x 256
    const int which = idx >> 12;                        // 4096 float4 per matrix
    const int e4 = idx & 4095;
    const float* src = (which == 0) ? Wq : (which == 1) ? Wk : Wv;
    float4 v = *(const float4*)(src + e4 * 4);
    uint2 o; o.x = cvtpk(v.x, v.y); o.y = cvtpk(v.z, v.w);
    *(uint2*)(Wb + ((size_t)which << 14) + e4 * 4) = o;
}

// ---------------------------------------------------------------------------
// Kernel 2: MFMA projections + residual + L2 norm (round-13 streaming version).
//   Qp  bf16 [b][o][n]  o-major, pre-scaled by log2(e)/||q||
//   Kh  bf16 [b][m][128] m-major
//   V2  bf16 [b][128 c][128 ch][32 m]  (8KB per 32-m chunk)
//   v0  fp32 -> out channels 0..127
// ---------------------------------------------------------------------------
__global__ __launch_bounds__(256, 2) void proj_kernel(
    const float* __restrict__ vol0, const float* __restrict__ vol1,
    const unsigned short* __restrict__ Wb, float* __restrict__ out,
    unsigned short* __restrict__ Qp, unsigned short* __restrict__ Kh,
    unsigned short* __restrict__ V2)
{
    __shared__ __align__(16) float xs[2][D_ * 64];   // [arr][d][64 n], staged by slice

    const int tid  = threadIdx.x;
    const int wave = tid >> 6, lane = tid & 63;
    const int l15  = lane & 15, lh = lane >> 4;

    const int bid = blockIdx.x;
    const int swz = (bid & 7) * 64 + (bid >> 3);     // XCD b owns batch b
    const int b   = swz >> 6;
    const int n0  = (swz & 63) * 64;

    auto stageslice = [&](int s) {
        #pragma unroll
        for (int a = 0; a < 2; ++a) {
            const char* src = (const char*)((a ? vol1 : vol0) + (size_t)b * D_ * N_ + n0);
            char* dstb = (char*)&xs[a][0];
            #pragma unroll
            for (int i = 0; i < 2; ++i) {
                int dst16 = (2 * s + i) * 4096 + tid * 16;
                int row = dst16 >> 8, cb = dst16 & 255;
                int rg = row >> 3;
                unsigned int key = (unsigned int)(((rg & 3) | ((rg & 1) << 2)) << 4);
                gll16(src + (size_t)row * (N_ * 4) + (cb ^ key), dstb + dst16);
            }
        }
    };

    const int nrow = wave * 16 + l15;

    auto afrag = [&](const float* base, int k) -> bf8 {
        const int dbase = k * 32 + lh * 8;
        const int rg = dbase >> 3;                    // = k*4 + lh
        const unsigned int key = (unsigned int)(((rg & 3) | ((rg & 1) << 2)) << 4);
        const unsigned int cb = ((unsigned int)(nrow * 4)) ^ key;
        const float* p = base + dbase * 64 + (cb >> 2);
        union { bf8 v; unsigned int w[4]; } u;
        #pragma unroll
        for (int jj = 0; jj < 4; ++jj)
            u.w[jj] = cvtpk(p[(2 * jj) * 64], p[(2 * jj + 1) * 64]);
        return u.v;
    };

    f4 aq[8], ak[8], a0v[8], a1v[8];
    #pragma unroll
    for (int ob = 0; ob < 8; ++ob) {
        aq[ob] = (f4){0.f,0.f,0.f,0.f}; ak[ob] = (f4){0.f,0.f,0.f,0.f};
        a0v[ob] = (f4){0.f,0.f,0.f,0.f}; a1v[ob] = (f4){0.f,0.f,0.f,0.f};
    }

    const unsigned short* Wqb = Wb;
    const unsigned short* Wkb = Wb + D_ * D_;
    const unsigned short* Wvb = Wb + 2 * D_ * D_;

    stageslice(0);
    stageslice(1);
    __syncthreads();

    #pragma unroll
    for (int k = 0; k < 4; ++k) {
        if (k < 2) stageslice(k + 2);    // issued at top -> full compute to land
        bf8 x0f = afrag(&xs[0][0], k);
        bf8 x1f = afrag(&xs[1][0], k);
        #pragma unroll
        for (int ob = 0; ob < 8; ++ob) {
            const size_t woff = ((size_t)(ob * 16 + l15)) * D_ + k * 32 + lh * 8;
            bf8 wq = *(const bf8*)(Wqb + woff);
            bf8 wk = *(const bf8*)(Wkb + woff);
            bf8 wv = *(const bf8*)(Wvb + woff);
            aq[ob]  = __builtin_amdgcn_mfma_f32_16x16x32_bf16(x0f, wq, aq[ob], 0, 0, 0);
            ak[ob]  = __builtin_amdgcn_mfma_f32_16x16x32_bf16(x1f, wk, ak[ob], 0, 0, 0);
            a0v[ob] = __builtin_amdgcn_mfma_f32_16x16x32_bf16(x0f, wv, a0v[ob], 0, 0, 0);
            a1v[ob] = __builtin_amdgcn_mfma_f32_16x16x32_bf16(x1f, wv, a1v[ob], 0, 0, 0);
        }
        if (k < 2) __syncthreads();      // publish slice k+2 (drained by compute k)
    }

    // ---- residual + norm partials: read x from GLOBAL (L2-hot), not LDS ----
    const int nbase = n0 + wave * 16 + lh * 4;
    float ssq[4] = {0.f,0.f,0.f,0.f}, ssk[4] = {0.f,0.f,0.f,0.f};
    #pragma unroll
    for (int ob = 0; ob < 8; ++ob) {
        const int o = ob * 16 + l15;
        f4 r0 = *(const f4*)(vol0 + ((size_t)(b * D_ + o)) * N_ + nbase);
        f4 r1 = *(const f4*)(vol1 + ((size_t)(b * D_ + o)) * N_ + nbase);
        #pragma unroll
        for (int r = 0; r < 4; ++r) {
            aq[ob][r] += r0[r]; ak[ob][r] += r1[r];
            a0v[ob][r] += r0[r]; a1v[ob][r] += r1[r];
            ssq[r] = fmaf(aq[ob][r], aq[ob][r], ssq[r]);
            ssk[r] = fmaf(ak[ob][r], ak[ob][r], ssk[r]);
        }
    }
    #pragma unroll
    for (int off = 1; off < 16; off <<= 1)
        #pragma unroll
        for (int r = 0; r < 4; ++r) {
            ssq[r] += __shfl_xor(ssq[r], off, 64);
            ssk[r] += __shfl_xor(ssk[r], off, 64);
        }
    float rq[4], rk[4];
    #pragma unroll
    for (int r = 0; r < 4; ++r) {
        rq[r] = 1.44269504088896f / fmaxf(sqrtf(ssq[r]), 1e-12f);
        rk[r] = 1.0f / fmaxf(sqrtf(ssk[r]), 1e-12f);
    }

    char* v2chunk = (char*)V2 + ((size_t)(b * 128 + (nbase >> 5))) * 8192
                  + (nbase & 31) * 2;

    #pragma unroll
    for (int ob = 0; ob < 8; ++ob) {
        const int o = ob * 16 + l15;
        *(f4*)(out + ((size_t)(b * CH + o)) * N_ + nbase) = a0v[ob];
        uint2 pv; pv.x = cvtpk(a1v[ob][0], a1v[ob][1]); pv.y = cvtpk(a1v[ob][2], a1v[ob][3]);
        *(uint2*)(v2chunk + (size_t)o * 64) = pv;
        uint2 pq; pq.x = cvtpk(aq[ob][0]*rq[0], aq[ob][1]*rq[1]);
        pq.y = cvtpk(aq[ob][2]*rq[2], aq[ob][3]*rq[3]);
        *(uint2*)(Qp + ((size_t)(b * D_ + o)) * N_ + nbase) = pq;
    }

    // Kh: per-wave LDS transpose chunk (xs dead after k-loop + barrier)
    __syncthreads();
    float* chunk = &xs[0][0] + wave * 2176;          // [128 o][17] fp32 per wave
    #pragma unroll
    for (int ob = 0; ob < 8; ++ob) {
        const int o = ob * 16 + l15;
        #pragma unroll
        for (int r = 0; r < 4; ++r) chunk[o * 17 + lh * 4 + r] = ak[ob][r] * rk[r];
    }
    asm volatile("s_waitcnt lgkmcnt(0)" ::: "memory");
    __builtin_amdgcn_sched_barrier(0);
    {
        const int o0 = (lane & 15) * 8, nr = lane >> 4;
        #pragma unroll
        for (int t = 0; t < 4; ++t) {
            int nl = t * 4 + nr;
            float f[8];
            #pragma unroll
            for (int j = 0; j < 8; ++j) f[j] = chunk[(o0 + j) * 17 + nl];
            uint4 st;
            st.x = cvtpk(f[0], f[1]); st.y = cvtpk(f[2], f[3]);
            st.z = cvtpk(f[4], f[5]); st.w = cvtpk(f[6], f[7]);
            *(uint4*)(Kh + ((size_t)(b * N_ + n0 + wave * 16 + nl)) * D_ + o0) = st;
        }
    }
}

// ---------------------------------------------------------------------------
// Kernel 3: attention, BARRIER-FREE inner loop (round-9 structure, with the
// launch-bounds spill bug fixed: (256,2) natural allocation, NOT (256,3)).
// 1024 blocks x 4 waves. Block owns 32 q-rows; wave = m-quarter (1024 m,
// 32 iters of 32-m). K and V both read directly from L2 (16B/lane
// contiguous); P is wave-private LDS (lgkmcnt + sched_barrier only).
// 4-way merge of acc + stats at the end through LDS (static acc indices).
// ---------------------------------------------------------------------------
__global__ __launch_bounds__(256, 2) void attn_kernel(
    const unsigned short* __restrict__ Qp, const unsigned short* __restrict__ Kh,
    const unsigned short* __restrict__ V2, float* __restrict__ out)
{
    __shared__ __align__(16) char smem[36864];
    // loop phase: P[wave] at smem + wave*2048 (8 KB total)
    // epilogue:  ex = (float*)smem [4w][8dc][16n][17]  (34816 B)
    //            stt = (float*)(smem+34816) [4w][2qg][16][4] (2048 B)

    const int tid  = threadIdx.x;
    const int wave = tid >> 6, lane = tid & 63;
    const int l15  = lane & 15, lh = lane >> 4;

    const int bid = blockIdx.x;
    const int swz = (bid & 7) * 128 + (bid >> 3);   // XCD = batch
    const int b   = swz >> 7;
    const int nw  = (swz & 127) * 32;               // block's 32 q-rows

    // ---- one-time Q gather (o-major Qp, pre-scaled by log2e/||q||) ----
    bf8 qf[2][4];
    const unsigned short* Qb = Qp + (size_t)b * D_ * N_;
    #pragma unroll
    for (int qg = 0; qg < 2; ++qg)
        #pragma unroll
        for (int dc = 0; dc < 4; ++dc) {
            union { bf8 v; unsigned short e[8]; } u;
            #pragma unroll
            for (int j = 0; j < 8; ++j)
                u.e[j] = Qb[((size_t)(dc * 32 + lh * 8 + j)) * N_ + nw + qg * 16 + l15];
            qf[qg][dc] = u.v;
        }

    f4 acc[2][8];
    #pragma unroll
    for (int qg = 0; qg < 2; ++qg)
        #pragma unroll
        for (int dc = 0; dc < 8; ++dc) acc[qg][dc] = (f4){0.f,0.f,0.f,0.f};
    float lsum[2] = {0.f, 0.f}, pu[2] = {0.f, 0.f}, pvv[2] = {0.f, 0.f};
    float Mp[2] = {-1e30f, -1e30f};

    float vb0[8];
    #pragma unroll
    for (int s = 0; s < 2; ++s)
        #pragma unroll
        for (int r = 0; r < 4; ++r)
            vb0[s * 4 + r] = -1.f + (2.f / 63.f) * (float)(s * 16 + lh * 4 + r);

    // direct-load bases (per-lane)
    const char* Kb = (const char*)(Kh + (size_t)b * N_ * D_)
                   + (size_t)(wave * 1024 + l15) * 256 + lh * 16;
    const char* Vb = (const char*)V2 + ((size_t)(b * 128 + wave * 32)) * 8192
                   + l15 * 64 + lh * 16;
    char* Pw = smem + wave * 2048;

    const unsigned int pkey  = ((unsigned int)((l15 >> 1) & 3)) << 4;
    const unsigned int prow0 = (unsigned int)(l15 * 64);
    const unsigned int prow1 = (unsigned int)((16 + l15) * 64);
    const unsigned int px    = ((unsigned int)(lh * 16)) ^ pkey;

    for (int t = 0; t < 32; ++t) {
        const int c = wave * 32 + t;           // global 32-m chunk index
        const char* kp = Kb + t * 8192;        // 32 rows x 256 B
        const char* vp = Vb + t * 8192;

        // ---- K frags (L2 direct): dc 0..3, m-halves 0/1
        bf8 k0[4], k1[4];
        #pragma unroll
        for (int dc = 0; dc < 4; ++dc) {
            k0[dc] = *(const bf8*)(kp + dc * 64);
            k1[dc] = *(const bf8*)(kp + 4096 + dc * 64);
        }
        // ---- V frags (L2 direct)
        bf8 vf[8];
        #pragma unroll
        for (int dc = 0; dc < 8; ++dc) vf[dc] = *(const bf8*)(vp + dc * 1024);

        // ---- QK^T swapped: lane: n = qg*16+l15, m = s*16+lh*4+r
        f4 s00 = (f4){0.f,0.f,0.f,0.f}, s01 = (f4){0.f,0.f,0.f,0.f};
        f4 s10 = (f4){0.f,0.f,0.f,0.f}, s11 = (f4){0.f,0.f,0.f,0.f};
        __builtin_amdgcn_s_setprio(1);
        #pragma unroll
        for (int dc = 0; dc < 4; ++dc) {
            s00 = __builtin_amdgcn_mfma_f32_16x16x32_bf16(k0[dc], qf[0][dc], s00, 0, 0, 0);
            s10 = __builtin_amdgcn_mfma_f32_16x16x32_bf16(k0[dc], qf[1][dc], s10, 0, 0, 0);
            s01 = __builtin_amdgcn_mfma_f32_16x16x32_bf16(k1[dc], qf[0][dc], s01, 0, 0, 0);
            s11 = __builtin_amdgcn_mfma_f32_16x16x32_bf16(k1[dc], qf[1][dc], s11, 0, 0, 0);
        }
        __builtin_amdgcn_s_setprio(0);

        // ---- softmax-lite + pos/denominator (f32 p)
        const float ut   = -1.f + (2.f / 63.f) * (float)(c >> 1);
        const float voff = (c & 1) ? (64.f / 63.f) : 0.f;
        #pragma unroll
        for (int qg = 0; qg < 2; ++qg) {
            f4 sa = qg ? s10 : s00, sb = qg ? s11 : s01;
            float p[8];
            #pragma unroll
            for (int r = 0; r < 4; ++r) {
                p[r]     = __builtin_amdgcn_exp2f(sa[r]);
                p[4 + r] = __builtin_amdgcn_exp2f(sb[r]);
            }
            Mp[qg] = fmaxf(Mp[qg], fmaxf(fmaxf(fmaxf(sa[0], sa[1]), fmaxf(sa[2], sa[3])),
                                         fmaxf(fmaxf(sb[0], sb[1]), fmaxf(sb[2], sb[3]))));
            float ps = ((p[0]+p[1]) + (p[2]+p[3])) + ((p[4]+p[5]) + (p[6]+p[7]));
            float pvp = 0.f;
            #pragma unroll
            for (int i = 0; i < 8; ++i) pvp = fmaf(vb0[i], p[i], pvp);
            lsum[qg] += ps;
            pu[qg]  = fmaf(ut, ps, pu[qg]);
            pvv[qg] = fmaf(voff, ps, pvv[qg] + pvp);
            const unsigned int pr = qg ? prow1 : prow0;
            uint2 w0; w0.x = cvtpk(p[0], p[1]); w0.y = cvtpk(p[2], p[3]);
            uint2 w1; w1.x = cvtpk(p[4], p[5]); w1.y = cvtpk(p[6], p[7]);
            *(uint2*)(Pw + pr + (((unsigned int)(lh * 8)) ^ pkey))      = w0;
            *(uint2*)(Pw + pr + (((unsigned int)(32 + lh * 8)) ^ pkey)) = w1;
        }
        asm volatile("s_waitcnt lgkmcnt(0)" ::: "memory");   // wave-local P order
        __builtin_amdgcn_sched_barrier(0);

        // ---- PV
        bf8 pf0 = *(const bf8*)(Pw + prow0 + px);
        bf8 pf1 = *(const bf8*)(Pw + prow1 + px);
        __builtin_amdgcn_s_setprio(1);
        #pragma unroll
        for (int dc = 0; dc < 8; ++dc) {
            acc[0][dc] = __builtin_amdgcn_mfma_f32_16x16x32_bf16(pf0, vf[dc], acc[0][dc], 0, 0, 0);
            acc[1][dc] = __builtin_amdgcn_mfma_f32_16x16x32_bf16(pf1, vf[dc], acc[1][dc], 0, 0, 0);
        }
        __builtin_amdgcn_s_setprio(0);
        // no barrier: waves fully independent
    }

    // ---- in-wave stats reduce over lh groups (per q-row l15)
    #pragma unroll
    for (int qg = 0; qg < 2; ++qg) {
        #pragma unroll
        for (int off = 16; off < 64; off <<= 1) {
            lsum[qg] += __shfl_xor(lsum[qg], off, 64);
            pu[qg]   += __shfl_xor(pu[qg], off, 64);
            pvv[qg]  += __shfl_xor(pvv[qg], off, 64);
            Mp[qg]    = fmaxf(Mp[qg], __shfl_xor(Mp[qg], off, 64));
        }
    }

    float* ex  = (float*)smem;               // [4w][8dc][16n][17]
    float* stt = (float*)(smem + 34816);     // [4w][2qg][16][4]

    __syncthreads();   // all waves done with loop (P regions dead)

    if (lane < 16) {
        #pragma unroll
        for (int qg = 0; qg < 2; ++qg) {
            float* s = stt + ((wave * 2 + qg) * 16 + l15) * 4;
            s[0] = lsum[qg]; s[1] = pu[qg]; s[2] = pvv[qg]; s[3] = Mp[qg];
        }
    }
    // qg0 acc -> ex (static indices)
    #pragma unroll
    for (int dc = 0; dc < 8; ++dc) {
        float* e = ex + (wave * 8 + dc) * 272 + (lh * 4) * 17 + l15;
        #pragma unroll
        for (int r = 0; r < 4; ++r) e[r * 17] = acc[0][dc][r];
    }
    __syncthreads();

    // merged stats (all waves compute identically)
    float rl[2], PUm[2], PVm[2], Mm[2];
    #pragma unroll
    for (int qg = 0; qg < 2; ++qg) {
        float Lm = 0.f, puM = 0.f, pvM = 0.f, mM = -1e30f;
        #pragma unroll
        for (int w = 0; w < 4; ++w) {
            const float* s = stt + ((w * 2 + qg) * 16 + l15) * 4;
            Lm += s[0]; puM += s[1]; pvM += s[2]; mM = fmaxf(mM, s[3]);
        }
        rl[qg] = __builtin_amdgcn_rcpf(Lm);
        PUm[qg] = puM; PVm[qg] = pvM; Mm[qg] = mM;
    }
    float rlr0[4], rlr1[4];
    #pragma unroll
    for (int r = 0; r < 4; ++r) {
        rlr0[r] = __shfl(rl[0], (lane & 48) + lh * 4 + r, 64);
        rlr1[r] = __shfl(rl[1], (lane & 48) + lh * 4 + r, 64);
    }

    // qg0 merge + store (each wave owns dc = 2*wave, 2*wave+1)
    #pragma unroll
    for (int jj = 0; jj < 2; ++jj) {
        const int dcow = wave * 2 + jj;                 // runtime: LDS addr only
        const float* e = ex + dcow * 272 + (lh * 4) * 17 + l15;
        f4 v;
        #pragma unroll
        for (int r = 0; r < 4; ++r)
            v[r] = (e[r*17] + e[2176 + r*17] + e[4352 + r*17] + e[6528 + r*17]) * rlr0[r];
        *(f4*)(out + ((size_t)(b * CH + 128 + dcow * 16 + l15)) * N_ + nw + lh * 4) = v;
    }
    __syncthreads();
    // qg1 acc -> ex
    #pragma unroll
    for (int dc = 0; dc < 8; ++dc) {
        float* e = ex + (wave * 8 + dc) * 272 + (lh * 4) * 17 + l15;
        #pragma unroll
        for (int r = 0; r < 4; ++r) e[r * 17] = acc[1][dc][r];
    }
    __syncthreads();
    #pragma unroll
    for (int jj = 0; jj < 2; ++jj) {
        const int dcow = wave * 2 + jj;
        const float* e = ex + dcow * 272 + (lh * 4) * 17 + l15;
        f4 v;
        #pragma unroll
        for (int r = 0; r < 4; ++r)
            v[r] = (e[r*17] + e[2176 + r*17] + e[4352 + r*17] + e[6528 + r*17]) * rlr1[r];
        *(f4*)(out + ((size_t)(b * CH + 128 + dcow * 16 + l15)) * N_ + nw + 16 + lh * 4) = v;
    }

    // pos + max channels (256,257,258): wave 0, lh==0 lanes (rows l15)
    if (wave == 0 && lh == 0) {
        #pragma unroll
        for (int qg = 0; qg < 2; ++qg) {
            const int gn = nw + qg * 16 + l15;
            out[((size_t)(b * CH + 256)) * N_ + gn] = PUm[qg] * rl[qg];
            out[((size_t)(b * CH + 257)) * N_ + gn] = PVm[qg] * rl[qg];
            out[((size_t)(b * CH + 258)) * N_ + gn] =
                __builtin_amdgcn_exp2f(Mm[qg]) * rl[qg];
        }
    }
}

// ---------------------------------------------------------------------------
extern "C" void kernel_launch(void* const* d_in, const int* in_sizes, int n_in,
                              void* d_out, int out_size, void* d_ws, size_t ws_size,
                              hipStream_t stream) {
    const float* vol0 = (const float*)d_in[0];
    const float* vol1 = (const float*)d_in[1];
    const float* Wq   = (const float*)d_in[2];
    const float* Wk   = (const float*)d_in[3];
    const float* Wv   = (const float*)d_in[4];
    float* out = (float*)d_out;

    char* ws = (char*)d_ws;
    const size_t QP_BYTES  = (size_t)B_ * D_ * N_ * 2;     // 8 MiB [b][o][n]
    const size_t KH_BYTES  = (size_t)B_ * N_ * D_ * 2;     // 8 MiB [b][m][d]
    const size_t V2_BYTES  = (size_t)B_ * D_ * N_ * 2;     // 8 MiB tiled
    unsigned short* Qp  = (unsigned short*)(ws);
    unsigned short* Kh  = (unsigned short*)(ws + QP_BYTES);
    unsigned short* V2  = (unsigned short*)(ws + QP_BYTES + KH_BYTES);
    unsigned short* Wb  = (unsigned short*)(ws + QP_BYTES + KH_BYTES + V2_BYTES);

    hipLaunchKernelGGL(wconv_kernel, dim3(48), dim3(256), 0, stream, Wq, Wk, Wv, Wb);
    hipLaunchKernelGGL(proj_kernel, dim3(512), dim3(256), 0, stream,
                       vol0, vol1, Wb, out, Qp, Kh, V2);
    hipLaunchKernelGGL(attn_kernel, dim3(1024), dim3(256), 0, stream,
                       Qp, Kh, V2, out);
}

// Round 15
// 124.483 us; speedup vs baseline: 1.7755x; 1.7755x over previous
//
#include <hip/hip_runtime.h>
#include <hip/hip_bf16.h>

// Problem constants (B, D, H, W) = (8, 128, 64, 64)
#define B_   8
#define D_   128
#define N_   4096
#define CH   259            // 2D+3 output channels

typedef short bf8 __attribute__((ext_vector_type(8)));   // 8 bf16 (MFMA A/B frag)
typedef float f4  __attribute__((ext_vector_type(4)));   // MFMA C/D frag

typedef unsigned int as1_u32 __attribute__((address_space(1)));
typedef unsigned int as3_u32 __attribute__((address_space(3)));

__device__ __forceinline__ void gll16(const void* g, void* l) {
    // async global->LDS, 16B/lane; LDS dest = wave-uniform base (HW adds lane*16)
    __builtin_amdgcn_global_load_lds((as1_u32*)(unsigned long long)g,
                                     (as3_u32*)(unsigned int)(unsigned long long)l,
                                     16, 0, 0);
}

__device__ __forceinline__ unsigned int cvtpk(float lo, float hi) {
    unsigned int r;
    asm("v_cvt_pk_bf16_f32 %0, %1, %2" : "=v"(r) : "v"(lo), "v"(hi));
    return r;
}

// ---------------------------------------------------------------------------
// Kernel 1: W fp32 -> bf16 (RNE), layout [3][o][d]. Vectorized: 12288 float4.
// ---------------------------------------------------------------------------
__global__ __launch_bounds__(256) void wconv_kernel(
    const float* __restrict__ Wq, const float* __restrict__ Wk,
    const float* __restrict__ Wv, unsigned short* __restrict__ Wb) {
    const int idx = blockIdx.x * 256 + threadIdx.x;     // 48 blocks x 256
    const int which = idx >> 12;                        // 4096 float4 per matrix
    const int e4 = idx & 4095;
    const float* src = (which == 0) ? Wq : (which == 1) ? Wk : Wv;
    float4 v = *(const float4*)(src + e4 * 4);
    uint2 o; o.x = cvtpk(v.x, v.y); o.y = cvtpk(v.z, v.w);
    *(uint2*)(Wb + ((size_t)which << 14) + e4 * 4) = o;
}

// ---------------------------------------------------------------------------
// Kernel 2: MFMA projections + residual + L2 norm (streaming k-slice version,
// round 13 — measured ~26 us). Residual/norm from global (L2-hot); afrag key
// (rg&3)|((rg&1)<<2) -> 2-way conflicts.
//   Qp  bf16 [b][o][n]  o-major, pre-scaled by log2(e)/||q||
//   Kh  bf16 [b][m][128] m-major
//   V2  bf16 [b][128 c][128 ch][32 m]  (8KB per 32-m chunk)
//   v0  fp32 -> out channels 0..127
// ---------------------------------------------------------------------------
__global__ __launch_bounds__(256, 2) void proj_kernel(
    const float* __restrict__ vol0, const float* __restrict__ vol1,
    const unsigned short* __restrict__ Wb, float* __restrict__ out,
    unsigned short* __restrict__ Qp, unsigned short* __restrict__ Kh,
    unsigned short* __restrict__ V2)
{
    __shared__ __align__(16) float xs[2][D_ * 64];   // [arr][d][64 n], staged by slice

    const int tid  = threadIdx.x;
    const int wave = tid >> 6, lane = tid & 63;
    const int l15  = lane & 15, lh = lane >> 4;

    const int bid = blockIdx.x;
    const int swz = (bid & 7) * 64 + (bid >> 3);     // XCD b owns batch b
    const int b   = swz >> 6;
    const int n0  = (swz & 63) * 64;

    auto stageslice = [&](int s) {
        #pragma unroll
        for (int a = 0; a < 2; ++a) {
            const char* src = (const char*)((a ? vol1 : vol0) + (size_t)b * D_ * N_ + n0);
            char* dstb = (char*)&xs[a][0];
            #pragma unroll
            for (int i = 0; i < 2; ++i) {
                int dst16 = (2 * s + i) * 4096 + tid * 16;
                int row = dst16 >> 8, cb = dst16 & 255;
                int rg = row >> 3;
                unsigned int key = (unsigned int)(((rg & 3) | ((rg & 1) << 2)) << 4);
                gll16(src + (size_t)row * (N_ * 4) + (cb ^ key), dstb + dst16);
            }
        }
    };

    const int nrow = wave * 16 + l15;

    auto afrag = [&](const float* base, int k) -> bf8 {
        const int dbase = k * 32 + lh * 8;
        const int rg = dbase >> 3;                    // = k*4 + lh
        const unsigned int key = (unsigned int)(((rg & 3) | ((rg & 1) << 2)) << 4);
        const unsigned int cb = ((unsigned int)(nrow * 4)) ^ key;
        const float* p = base + dbase * 64 + (cb >> 2);
        union { bf8 v; unsigned int w[4]; } u;
        #pragma unroll
        for (int jj = 0; jj < 4; ++jj)
            u.w[jj] = cvtpk(p[(2 * jj) * 64], p[(2 * jj + 1) * 64]);
        return u.v;
    };

    f4 aq[8], ak[8], a0v[8], a1v[8];
    #pragma unroll
    for (int ob = 0; ob < 8; ++ob) {
        aq[ob] = (f4){0.f,0.f,0.f,0.f}; ak[ob] = (f4){0.f,0.f,0.f,0.f};
        a0v[ob] = (f4){0.f,0.f,0.f,0.f}; a1v[ob] = (f4){0.f,0.f,0.f,0.f};
    }

    const unsigned short* Wqb = Wb;
    const unsigned short* Wkb = Wb + D_ * D_;
    const unsigned short* Wvb = Wb + 2 * D_ * D_;

    stageslice(0);
    stageslice(1);
    __syncthreads();

    #pragma unroll
    for (int k = 0; k < 4; ++k) {
        if (k < 2) stageslice(k + 2);    // issued at top -> full compute to land
        bf8 x0f = afrag(&xs[0][0], k);
        bf8 x1f = afrag(&xs[1][0], k);
        #pragma unroll
        for (int ob = 0; ob < 8; ++ob) {
            const size_t woff = ((size_t)(ob * 16 + l15)) * D_ + k * 32 + lh * 8;
            bf8 wq = *(const bf8*)(Wqb + woff);
            bf8 wk = *(const bf8*)(Wkb + woff);
            bf8 wv = *(const bf8*)(Wvb + woff);
            aq[ob]  = __builtin_amdgcn_mfma_f32_16x16x32_bf16(x0f, wq, aq[ob], 0, 0, 0);
            ak[ob]  = __builtin_amdgcn_mfma_f32_16x16x32_bf16(x1f, wk, ak[ob], 0, 0, 0);
            a0v[ob] = __builtin_amdgcn_mfma_f32_16x16x32_bf16(x0f, wv, a0v[ob], 0, 0, 0);
            a1v[ob] = __builtin_amdgcn_mfma_f32_16x16x32_bf16(x1f, wv, a1v[ob], 0, 0, 0);
        }
        if (k < 2) __syncthreads();      // publish slice k+2 (drained by compute k)
    }

    // ---- residual + norm partials: read x from GLOBAL (L2-hot), not LDS ----
    const int nbase = n0 + wave * 16 + lh * 4;
    float ssq[4] = {0.f,0.f,0.f,0.f}, ssk[4] = {0.f,0.f,0.f,0.f};
    #pragma unroll
    for (int ob = 0; ob < 8; ++ob) {
        const int o = ob * 16 + l15;
        f4 r0 = *(const f4*)(vol0 + ((size_t)(b * D_ + o)) * N_ + nbase);
        f4 r1 = *(const f4*)(vol1 + ((size_t)(b * D_ + o)) * N_ + nbase);
        #pragma unroll
        for (int r = 0; r < 4; ++r) {
            aq[ob][r] += r0[r]; ak[ob][r] += r1[r];
            a0v[ob][r] += r0[r]; a1v[ob][r] += r1[r];
            ssq[r] = fmaf(aq[ob][r], aq[ob][r], ssq[r]);
            ssk[r] = fmaf(ak[ob][r], ak[ob][r], ssk[r]);
        }
    }
    #pragma unroll
    for (int off = 1; off < 16; off <<= 1)
        #pragma unroll
        for (int r = 0; r < 4; ++r) {
            ssq[r] += __shfl_xor(ssq[r], off, 64);
            ssk[r] += __shfl_xor(ssk[r], off, 64);
        }
    float rq[4], rk[4];
    #pragma unroll
    for (int r = 0; r < 4; ++r) {
        rq[r] = 1.44269504088896f / fmaxf(sqrtf(ssq[r]), 1e-12f);
        rk[r] = 1.0f / fmaxf(sqrtf(ssk[r]), 1e-12f);
    }

    char* v2chunk = (char*)V2 + ((size_t)(b * 128 + (nbase >> 5))) * 8192
                  + (nbase & 31) * 2;

    #pragma unroll
    for (int ob = 0; ob < 8; ++ob) {
        const int o = ob * 16 + l15;
        *(f4*)(out + ((size_t)(b * CH + o)) * N_ + nbase) = a0v[ob];
        uint2 pv; pv.x = cvtpk(a1v[ob][0], a1v[ob][1]); pv.y = cvtpk(a1v[ob][2], a1v[ob][3]);
        *(uint2*)(v2chunk + (size_t)o * 64) = pv;
        uint2 pq; pq.x = cvtpk(aq[ob][0]*rq[0], aq[ob][1]*rq[1]);
        pq.y = cvtpk(aq[ob][2]*rq[2], aq[ob][3]*rq[3]);
        *(uint2*)(Qp + ((size_t)(b * D_ + o)) * N_ + nbase) = pq;
    }

    // Kh: per-wave LDS transpose chunk (xs dead after k-loop + barrier)
    __syncthreads();
    float* chunk = &xs[0][0] + wave * 2176;          // [128 o][17] fp32 per wave
    #pragma unroll
    for (int ob = 0; ob < 8; ++ob) {
        const int o = ob * 16 + l15;
        #pragma unroll
        for (int r = 0; r < 4; ++r) chunk[o * 17 + lh * 4 + r] = ak[ob][r] * rk[r];
    }
    asm volatile("s_waitcnt lgkmcnt(0)" ::: "memory");
    __builtin_amdgcn_sched_barrier(0);
    {
        const int o0 = (lane & 15) * 8, nr = lane >> 4;
        #pragma unroll
        for (int t = 0; t < 4; ++t) {
            int nl = t * 4 + nr;
            float f[8];
            #pragma unroll
            for (int j = 0; j < 8; ++j) f[j] = chunk[(o0 + j) * 17 + nl];
            uint4 st;
            st.x = cvtpk(f[0], f[1]); st.y = cvtpk(f[2], f[3]);
            st.z = cvtpk(f[4], f[5]); st.w = cvtpk(f[6], f[7]);
            *(uint4*)(Kh + ((size_t)(b * N_ + n0 + wave * 16 + nl)) * D_ + o0) = st;
        }
    }
}

// ---------------------------------------------------------------------------
// Kernel 3: attention — round-11 structure, the measured optimum (96.8 us)
// across 4 tested architectures (V-direct 97.7, K+V-LDS 96.8, SW-pipelined
// 100.5, barrier-free-direct 191.7). Limiter: register-capped 2 waves/SIMD
// (acc 64 + qf 32 + state ~= 176 unified regs) x partially-overlapped
// MFMA/VALU/LDS chain. 128 q-rows/block, 8 waves = (qquad x mhalf),
// K+V gll16-staged shared x4, double-buffered, 1 block/CU.
// ---------------------------------------------------------------------------
__global__ __launch_bounds__(512, 2) void attn_kernel(
    const unsigned short* __restrict__ Qp, const unsigned short* __restrict__ Kh,
    const unsigned short* __restrict__ V2, float* __restrict__ out)
{
    __shared__ __align__(16) char smem[81920];
    char* KB = smem;            // [2 buf][2 mh][32 m][256B] = 32 KB
    char* VB = smem + 32768;    // [2 buf][2 mh][128 ch][64B] = 32 KB
    char* PB = smem + 65536;    // [8 wave][32 n][64B] = 16 KB

    const int tid  = threadIdx.x;
    const int wave = tid >> 6, lane = tid & 63;
    const int l15  = lane & 15, lh = lane >> 4;
    const int mhalf = wave & 1, qquad = wave >> 1;

    const int bid = blockIdx.x;
    const int swz = (bid & 7) * 32 + (bid >> 3);    // XCD = batch
    const int b   = swz >> 5;
    const int n0  = (swz & 31) * 128;
    const int nw  = n0 + qquad * 32;                // this wave's 32 q-rows

    // ---- one-time Q gather (o-major Qp, pre-scaled by log2e/||q||) ----
    bf8 qf[2][4];
    const unsigned short* Qb = Qp + (size_t)b * D_ * N_;
    #pragma unroll
    for (int qg = 0; qg < 2; ++qg)
        #pragma unroll
        for (int dc = 0; dc < 4; ++dc) {
            union { bf8 v; unsigned short e[8]; } u;
            #pragma unroll
            for (int j = 0; j < 8; ++j)
                u.e[j] = Qb[((size_t)(dc * 32 + lh * 8 + j)) * N_ + nw + qg * 16 + l15];
            qf[qg][dc] = u.v;
        }

    f4 acc[2][8];
    #pragma unroll
    for (int qg = 0; qg < 2; ++qg)
        #pragma unroll
        for (int dc = 0; dc < 8; ++dc) acc[qg][dc] = (f4){0.f,0.f,0.f,0.f};
    float lsum[2] = {0.f, 0.f}, pu[2] = {0.f, 0.f}, pvv[2] = {0.f, 0.f};
    float Mp[2] = {-1e30f, -1e30f};

    float vb0[8];
    #pragma unroll
    for (int s = 0; s < 2; ++s)
        #pragma unroll
        for (int r = 0; r < 4; ++r)
            vb0[s * 4 + r] = -1.f + (2.f / 63.f) * (float)(s * 16 + lh * 4 + r);

    const char* Kbytes = (const char*)(Kh + (size_t)b * N_ * D_);
    const char* Vbytes = (const char*)V2 + ((size_t)b * 128) * 8192;
    char* Pw = PB + wave * 2048;

    // cooperative staging: waves 0-3 stage K (16KB), waves 4-7 stage V (16KB)
    const int sK = (wave < 4);
    const int smh = sK ? (wave >> 1) : ((wave - 4) >> 1);   // which m-half
    const int spt = sK ? (wave & 1) : ((wave - 4) & 1);     // which part
    unsigned int soffs[4];
    #pragma unroll
    for (int ii = 0; ii < 4; ++ii) {
        if (sK) {
            int rr = spt * 16 + ii * 4 + (lane >> 4);       // m-row 0..31
            unsigned int col = (unsigned int)((lane & 15) * 16);
            soffs[ii] = (unsigned int)(rr * 256) + (col ^ (unsigned int)((rr & 7) << 4));
        } else {
            int vr = spt * 64 + ii * 16 + (lane >> 2);      // ch-row 0..127
            unsigned int mc = (unsigned int)((lane & 3) * 16);
            soffs[ii] = (unsigned int)(vr * 64) + (mc ^ (unsigned int)(((vr >> 1) & 3) << 4));
        }
    }
    auto stage = [&](int buf, int t) {
        if (sK) {
            const char* ks = Kbytes + (size_t)smh * 524288 + (size_t)t * 8192;
            char* kd = KB + buf * 16384 + smh * 8192 + spt * 4096;
            #pragma unroll
            for (int ii = 0; ii < 4; ++ii) gll16(ks + soffs[ii], kd + ii * 1024);
        } else {
            const char* vs = Vbytes + ((size_t)(smh * 64 + t)) * 8192;
            char* vd = VB + buf * 16384 + smh * 8192 + spt * 4096;
            #pragma unroll
            for (int ii = 0; ii < 4; ++ii) gll16(vs + soffs[ii], vd + ii * 1024);
        }
    };

    // read-side offsets
    unsigned int kcol[4];
    #pragma unroll
    for (int dc = 0; dc < 4; ++dc)
        kcol[dc] = ((unsigned int)(dc * 64 + lh * 16)) ^ ((unsigned int)((l15 & 7) << 4));
    const unsigned int pkey  = ((unsigned int)((l15 >> 1) & 3)) << 4;
    const unsigned int prow0 = (unsigned int)(l15 * 64);
    const unsigned int prow1 = (unsigned int)((16 + l15) * 64);
    const unsigned int px    = ((unsigned int)(lh * 16)) ^ pkey;
    const unsigned int vxx   = ((unsigned int)(lh * 16)) ^ pkey;   // V read xor

    stage(0, 0);
    __syncthreads();

    for (int t = 0; t < 64; ++t) {
        const int cur = t & 1;
        if (t + 1 < 64) stage(cur ^ 1, t + 1);   // async K+V prefetch

        const char* Kc = KB + cur * 16384 + mhalf * 8192 + l15 * 256;
        const char* Vc = VB + cur * 16384 + mhalf * 8192 + l15 * 64 + vxx;
        const int c = mhalf * 64 + t;            // global 32-m chunk index

        // ---- QK^T swapped: lane holds n = qg*16+l15, m = s*16+lh*4+r
        f4 s00 = (f4){0.f,0.f,0.f,0.f}, s01 = (f4){0.f,0.f,0.f,0.f};
        f4 s10 = (f4){0.f,0.f,0.f,0.f}, s11 = (f4){0.f,0.f,0.f,0.f};
        __builtin_amdgcn_s_setprio(1);
        #pragma unroll
        for (int dc = 0; dc < 4; ++dc) {
            bf8 k0 = *(const bf8*)(Kc + kcol[dc]);
            bf8 k1 = *(const bf8*)(Kc + 4096 + kcol[dc]);
            s00 = __builtin_amdgcn_mfma_f32_16x16x32_bf16(k0, qf[0][dc], s00, 0, 0, 0);
            s10 = __builtin_amdgcn_mfma_f32_16x16x32_bf16(k0, qf[1][dc], s10, 0, 0, 0);
            s01 = __builtin_amdgcn_mfma_f32_16x16x32_bf16(k1, qf[0][dc], s01, 0, 0, 0);
            s11 = __builtin_amdgcn_mfma_f32_16x16x32_bf16(k1, qf[1][dc], s11, 0, 0, 0);
        }
        __builtin_amdgcn_s_setprio(0);

        // ---- softmax-lite + pos/denominator (f32 p)
        const float ut   = -1.f + (2.f / 63.f) * (float)(c >> 1);
        const float voff = (c & 1) ? (64.f / 63.f) : 0.f;
        #pragma unroll
        for (int qg = 0; qg < 2; ++qg) {
            f4 sa = qg ? s10 : s00, sb = qg ? s11 : s01;
            float p[8];
            #pragma unroll
            for (int r = 0; r < 4; ++r) {
                p[r]     = __builtin_amdgcn_exp2f(sa[r]);
                p[4 + r] = __builtin_amdgcn_exp2f(sb[r]);
            }
            Mp[qg] = fmaxf(Mp[qg], fmaxf(fmaxf(fmaxf(sa[0], sa[1]), fmaxf(sa[2], sa[3])),
                                         fmaxf(fmaxf(sb[0], sb[1]), fmaxf(sb[2], sb[3]))));
            float ps = ((p[0]+p[1]) + (p[2]+p[3])) + ((p[4]+p[5]) + (p[6]+p[7]));
            float pvp = 0.f;
            #pragma unroll
            for (int i = 0; i < 8; ++i) pvp = fmaf(vb0[i], p[i], pvp);
            lsum[qg] += ps;
            pu[qg]  = fmaf(ut, ps, pu[qg]);
            pvv[qg] = fmaf(voff, ps, pvv[qg] + pvp);
            const unsigned int pr = qg ? prow1 : prow0;
            uint2 w0; w0.x = cvtpk(p[0], p[1]); w0.y = cvtpk(p[2], p[3]);
            uint2 w1; w1.x = cvtpk(p[4], p[5]); w1.y = cvtpk(p[6], p[7]);
            *(uint2*)(Pw + pr + (((unsigned int)(lh * 8)) ^ pkey))      = w0;
            *(uint2*)(Pw + pr + (((unsigned int)(32 + lh * 8)) ^ pkey)) = w1;
        }
        asm volatile("s_waitcnt lgkmcnt(0)" ::: "memory");   // wave-local P order
        __builtin_amdgcn_sched_barrier(0);

        // ---- PV: pf per qg, vf from LDS (shared across the 4 qquad waves)
        bf8 pf0 = *(const bf8*)(Pw + prow0 + px);
        bf8 pf1 = *(const bf8*)(Pw + prow1 + px);
        __builtin_amdgcn_s_setprio(1);
        #pragma unroll
        for (int dc = 0; dc < 8; ++dc) {
            bf8 vfd = *(const bf8*)(Vc + dc * 1024);
            acc[0][dc] = __builtin_amdgcn_mfma_f32_16x16x32_bf16(pf0, vfd, acc[0][dc], 0, 0, 0);
            acc[1][dc] = __builtin_amdgcn_mfma_f32_16x16x32_bf16(pf1, vfd, acc[1][dc], 0, 0, 0);
        }
        __builtin_amdgcn_s_setprio(0);
        __syncthreads();   // next-iter K/V staged; WAR on shared buffers
    }

    // ---- in-wave stats reduce over lh groups (per q-row l15)
    #pragma unroll
    for (int qg = 0; qg < 2; ++qg) {
        #pragma unroll
        for (int off = 16; off < 64; off <<= 1) {
            lsum[qg] += __shfl_xor(lsum[qg], off, 64);
            pu[qg]   += __shfl_xor(pu[qg], off, 64);
            pvv[qg]  += __shfl_xor(pvv[qg], off, 64);
            Mp[qg]    = fmaxf(Mp[qg], __shfl_xor(Mp[qg], off, 64));
        }
    }

    // ---- mhalf-pair merge via LDS (K/V/P regions dead) ----
    __syncthreads();
    float* ex  = (float*)smem;               // [8w][2qg][4dc][16][17] = 69632 B
    float* stt = (float*)(smem + 69632);     // [8w][2qg][16][4] = 4096 B
    if (lane < 16) {
        #pragma unroll
        for (int qg = 0; qg < 2; ++qg) {
            float* s = stt + ((wave * 2 + qg) * 16 + l15) * 4;
            s[0] = lsum[qg]; s[1] = pu[qg]; s[2] = pvv[qg]; s[3] = Mp[qg];
        }
    }
    // provide the dc-range the PARTNER outputs (compile-time acc indices)
    #pragma unroll
    for (int qg = 0; qg < 2; ++qg)
        #pragma unroll
        for (int j = 0; j < 4; ++j) {
            float* e = ex + (((wave * 2 + qg) * 4 + j) * 16 + lh * 4) * 17 + l15;
            if (mhalf == 0) {
                #pragma unroll
                for (int r = 0; r < 4; ++r) e[r * 17] = acc[qg][4 + j][r];
            } else {
                #pragma unroll
                for (int r = 0; r < 4; ++r) e[r * 17] = acc[qg][j][r];
            }
        }
    __syncthreads();

    const int pw_ = wave ^ 1;                // same qquad, other mhalf
    float rl[2], PUm[2], PVm[2], Mm[2];
    #pragma unroll
    for (int qg = 0; qg < 2; ++qg) {
        const float* s = stt + ((pw_ * 2 + qg) * 16 + l15) * 4;
        float Lm = lsum[qg] + s[0];
        PUm[qg] = pu[qg]  + s[1];
        PVm[qg] = pvv[qg] + s[2];
        Mm[qg]  = fmaxf(Mp[qg], s[3]);
        rl[qg]  = __builtin_amdgcn_rcpf(Lm);
    }

    // ---- v1w stores: merged acc (compile-time acc indices per branch)
    #pragma unroll
    for (int qg = 0; qg < 2; ++qg) {
        float rlr[4];
        #pragma unroll
        for (int r = 0; r < 4; ++r)
            rlr[r] = __shfl(rl[qg], (lane & 48) + lh * 4 + r, 64);
        #pragma unroll
        for (int j = 0; j < 4; ++j) {
            const float* e = ex + (((pw_ * 2 + qg) * 4 + j) * 16 + lh * 4) * 17 + l15;
            f4 v;
            if (mhalf == 0) {
                #pragma unroll
                for (int r = 0; r < 4; ++r) v[r] = (acc[qg][j][r] + e[r * 17]) * rlr[r];
            } else {
                #pragma unroll
                for (int r = 0; r < 4; ++r) v[r] = (acc[qg][4 + j][r] + e[r * 17]) * rlr[r];
            }
            const int och = 128 + (mhalf * 4 + j) * 16 + l15;   // scalar math only
            *(f4*)(out + ((size_t)(b * CH + och)) * N_ + nw + qg * 16 + lh * 4) = v;
        }
    }
    // ---- pos + max channels (256,257,258): mhalf-0 waves, lh==0
    if (mhalf == 0 && lh == 0) {
        #pragma unroll
        for (int qg = 0; qg < 2; ++qg) {
            const int gn = nw + qg * 16 + l15;
            out[((size_t)(b * CH + 256)) * N_ + gn] = PUm[qg] * rl[qg];
            out[((size_t)(b * CH + 257)) * N_ + gn] = PVm[qg] * rl[qg];
            out[((size_t)(b * CH + 258)) * N_ + gn] =
                __builtin_amdgcn_exp2f(Mm[qg]) * rl[qg];
        }
    }
}

// ---------------------------------------------------------------------------
extern "C" void kernel_launch(void* const* d_in, const int* in_sizes, int n_in,
                              void* d_out, int out_size, void* d_ws, size_t ws_size,
                              hipStream_t stream) {
    const float* vol0 = (const float*)d_in[0];
    const float* vol1 = (const float*)d_in[1];
    const float* Wq   = (const float*)d_in[2];
    const float* Wk   = (const float*)d_in[3];
    const float* Wv   = (const float*)d_in[4];
    float* out = (float*)d_out;

    char* ws = (char*)d_ws;
    const size_t QP_BYTES  = (size_t)B_ * D_ * N_ * 2;     // 8 MiB [b][o][n]
    const size_t KH_BYTES  = (size_t)B_ * N_ * D_ * 2;     // 8 MiB [b][m][d]
    const size_t V2_BYTES  = (size_t)B_ * D_ * N_ * 2;     // 8 MiB tiled
    unsigned short* Qp  = (unsigned short*)(ws);
    unsigned short* Kh  = (unsigned short*)(ws + QP_BYTES);
    unsigned short* V2  = (unsigned short*)(ws + QP_BYTES + KH_BYTES);
    unsigned short* Wb  = (unsigned short*)(ws + QP_BYTES + KH_BYTES + V2_BYTES);

    hipLaunchKernelGGL(wconv_kernel, dim3(48), dim3(256), 0, stream, Wq, Wk, Wv, Wb);
    hipLaunchKernelGGL(proj_kernel, dim3(512), dim3(256), 0, stream,
                       vol0, vol1, Wb, out, Qp, Kh, V2);
    hipLaunchKernelGGL(attn_kernel, dim3(256), dim3(512), 0, stream,
                       Qp, Kh, V2, out);
}